// Round 1
// baseline (1923.217 us; speedup 1.0000x reference)
//
#include <hip/hip_runtime.h>
#include <hip/hip_bf16.h>
#include <math.h>

// Problem constants (reference: B=64, L=1024, H=64, VOCAB=64)
#define BB 64
#define LL 1024
#define HH 64
#define TSCALE2 0.4f

// ---------------------------------------------------------------------------
// Kernel 1: per-token phase.
// block = 256 threads (4 waves), 32 tokens/block, grid = 65536/32 = 2048.
// Computes hn = LN(h + FF(h)), then kn/v (t<1023) or q (t==1023).
// ---------------------------------------------------------------------------
__global__ __launch_bounds__(256, 1)
void token_kernel(const int* __restrict__ seq,
                  const float* __restrict__ embed_W,
                  const float* __restrict__ ff_W1, const float* __restrict__ ff_b1,
                  const float* __restrict__ ff_W2, const float* __restrict__ ff_b2,
                  const float* __restrict__ ln_g, const float* __restrict__ ln_b,
                  const float* __restrict__ kp_W, const float* __restrict__ vp_W,
                  const float* __restrict__ qp_W,
                  float* __restrict__ kn_all, float* __restrict__ v_all,
                  float* __restrict__ vn2_all, float* __restrict__ qbuf)
{
    __shared__ __align__(16) float h_s[32][64];    // 8 KB
    __shared__ __align__(16) float t1_s[32][128];  // 16 KB
    __shared__ __align__(16) float hn_s[32][64];   // 8 KB

    const int tid  = threadIdx.x;
    const int tok0 = blockIdx.x * 32;

    // ---- Stage A: embedding gather into LDS (coalesced per 64-elem row) ----
#pragma unroll
    for (int k = 0; k < 8; ++k) {
        int e   = k * 256 + tid;
        int tok = e >> 6, i = e & 63;
        int s   = seq[tok0 + tok];
        h_s[tok][i] = embed_W[s * 64 + i];
    }
    __syncthreads();

    // ---- Stage B: FF1 (64 -> 128, ReLU). thread: col j = tid&127, 16 toks ----
    {
        const int j = tid & 127;
        const int g = tid >> 7;           // 0 or 1 -> token half
        float w1c[64];
#pragma unroll
        for (int ii = 0; ii < 64; ++ii) w1c[ii] = ff_W1[ii * 128 + j];
        const float b1j = ff_b1[j];
#pragma unroll
        for (int tk = 0; tk < 16; ++tk) {
            const int tok = g * 16 + tk;
            const float4* h4 = (const float4*)h_s[tok];
            float a0 = b1j, a1 = 0.f, a2 = 0.f, a3 = 0.f;
#pragma unroll
            for (int w = 0; w < 16; ++w) {
                float4 hv = h4[w];
                a0 = fmaf(hv.x, w1c[4*w+0], a0);
                a1 = fmaf(hv.y, w1c[4*w+1], a1);
                a2 = fmaf(hv.z, w1c[4*w+2], a2);
                a3 = fmaf(hv.w, w1c[4*w+3], a3);
            }
            float acc = (a0 + a1) + (a2 + a3);
            t1_s[tok][j] = fmaxf(acc, 0.f);
        }
    }
    __syncthreads();

    // ---- Stage C: FF2 (128 -> 64) + residual + LayerNorm. i = tid&63 ----
    {
        const int i  = tid & 63;          // == lane id within wave
        const int w4 = tid >> 6;          // wave id 0..3 -> 8 tokens each
        float w2c[128];
#pragma unroll
        for (int jj = 0; jj < 128; ++jj) w2c[jj] = ff_W2[jj * 64 + i];
        const float b2i = ff_b2[i];
        const float gi  = ln_g[i];
        const float bi  = ln_b[i];
#pragma unroll
        for (int tk = 0; tk < 8; ++tk) {
            const int tok = w4 * 8 + tk;
            const float4* t4 = (const float4*)t1_s[tok];
            float a0 = b2i, a1 = 0.f, a2 = 0.f, a3 = 0.f;
#pragma unroll
            for (int w = 0; w < 32; ++w) {
                float4 tv = t4[w];
                a0 = fmaf(tv.x, w2c[4*w+0], a0);
                a1 = fmaf(tv.y, w2c[4*w+1], a1);
                a2 = fmaf(tv.z, w2c[4*w+2], a2);
                a3 = fmaf(tv.w, w2c[4*w+3], a3);
            }
            float x = h_s[tok][i] + ((a0 + a1) + (a2 + a3));
            // two-pass LayerNorm (matches reference formula)
            float s = x;
#pragma unroll
            for (int m = 32; m > 0; m >>= 1) s += __shfl_xor(s, m);
            float mu = s * (1.f / 64.f);
            float d  = x - mu;
            float s2 = d * d;
#pragma unroll
            for (int m = 32; m > 0; m >>= 1) s2 += __shfl_xor(s2, m);
            float var = s2 * (1.f / 64.f);
            hn_s[tok][i] = d / sqrtf(var + 1e-5f) * gi + bi;
        }
    }
    __syncthreads();

    // ---- Stage D: k,v projections + kn normalize (t<1023) OR q (t==1023) ----
    {
        const int i  = tid & 63;
        const int w4 = tid >> 6;
        float kc[64], vc[64];
#pragma unroll
        for (int ii = 0; ii < 64; ++ii) {
            kc[ii] = kp_W[ii * 64 + i];
            vc[ii] = vp_W[ii * 64 + i];
        }
#pragma unroll
        for (int tk = 0; tk < 8; ++tk) {
            const int tok = w4 * 8 + tk;
            const int tg  = tok0 + tok;
            const int b   = tg >> 10;
            const int t   = tg & 1023;
            const float4* hn4 = (const float4*)hn_s[tok];
            if (t < 1023) {
                float ka0=0.f,ka1=0.f,ka2=0.f,ka3=0.f;
                float va0=0.f,va1=0.f,va2=0.f,va3=0.f;
#pragma unroll
                for (int w = 0; w < 16; ++w) {
                    float4 hv = hn4[w];
                    ka0 = fmaf(hv.x, kc[4*w+0], ka0);
                    ka1 = fmaf(hv.y, kc[4*w+1], ka1);
                    ka2 = fmaf(hv.z, kc[4*w+2], ka2);
                    ka3 = fmaf(hv.w, kc[4*w+3], ka3);
                    va0 = fmaf(hv.x, vc[4*w+0], va0);
                    va1 = fmaf(hv.y, vc[4*w+1], va1);
                    va2 = fmaf(hv.z, vc[4*w+2], va2);
                    va3 = fmaf(hv.w, vc[4*w+3], va3);
                }
                float ka = (ka0 + ka1) + (ka2 + ka3);
                float va = (va0 + va1) + (va2 + va3);
                float kn2 = ka * ka, vn2 = va * va;
#pragma unroll
                for (int m = 32; m > 0; m >>= 1) {
                    kn2 += __shfl_xor(kn2, m);
                    vn2 += __shfl_xor(vn2, m);
                }
                float knorm = fmaxf(sqrtf(kn2), 1e-12f);
                size_t idx = ((size_t)b * 1023 + t) * 64 + i;
                kn_all[idx] = ka / knorm;
                v_all[idx]  = va;
                if (i == 0) vn2_all[b * 1023 + t] = vn2;
            } else {
                // q = hn @ qp_W  (one token per batch)
                float qa0=0.f,qa1=0.f,qa2=0.f,qa3=0.f;
#pragma unroll
                for (int w = 0; w < 16; ++w) {
                    float4 hv = hn4[w];
                    qa0 = fmaf(hv.x, qp_W[(4*w+0)*64 + i], qa0);
                    qa1 = fmaf(hv.y, qp_W[(4*w+1)*64 + i], qa1);
                    qa2 = fmaf(hv.z, qp_W[(4*w+2)*64 + i], qa2);
                    qa3 = fmaf(hv.w, qp_W[(4*w+3)*64 + i], qa3);
                }
                qbuf[b * 64 + i] = (qa0 + qa1) + (qa2 + qa3);
            }
        }
    }
}

// ---------------------------------------------------------------------------
// Kernel 2: sequential fast-weight scan + output head.
// grid = 64 (one block/batch), block = 64 (one wave). Lane i owns M row i.
// ---------------------------------------------------------------------------
__device__ __forceinline__ void load_step(const float* __restrict__ knb,
                                          const float* __restrict__ vb,
                                          const float* __restrict__ v2b,
                                          int t, int lane,
                                          float4 (&ck)[16], float& vi, float& vn2)
{
    const float4* p = (const float4*)(knb + (size_t)t * 64);
#pragma unroll
    for (int w = 0; w < 16; ++w) ck[w] = p[w];   // broadcast: all lanes same addr
    vi  = vb[(size_t)t * 64 + lane];
    vn2 = v2b[t];
}

__device__ __forceinline__ void scan_step(float (&M)[64], const float4 (&ck)[16],
                                          float vi, float vn2)
{
    float a0 = 0.f, a1 = 0.f, a2 = 0.f, a3 = 0.f;
#pragma unroll
    for (int w = 0; w < 16; ++w) {
        a0 = fmaf(M[4*w+0], ck[w].x, a0);
        a1 = fmaf(M[4*w+1], ck[w].y, a1);
        a2 = fmaf(M[4*w+2], ck[w].z, a2);
        a3 = fmaf(M[4*w+3], ck[w].w, a3);
    }
    float vp = (a0 + a1) + (a2 + a3);
    float d  = vi - vp;
    float e  = d * d;
#pragma unroll
    for (int m = 32; m > 0; m >>= 1) e += __shfl_xor(e, m);
    // gate: err > 0.4 * ||v||  (wave-uniform branch)
    if (sqrtf(e) > TSCALE2 * sqrtf(vn2)) {
#pragma unroll
        for (int w = 0; w < 16; ++w) {
            M[4*w+0] = fmaf(d, ck[w].x, M[4*w+0]);
            M[4*w+1] = fmaf(d, ck[w].y, M[4*w+1]);
            M[4*w+2] = fmaf(d, ck[w].z, M[4*w+2]);
            M[4*w+3] = fmaf(d, ck[w].w, M[4*w+3]);
        }
    }
}

__global__ __launch_bounds__(64, 1)
void scan_kernel(const float* __restrict__ kn_all,
                 const float* __restrict__ v_all,
                 const float* __restrict__ vn2_all,
                 const float* __restrict__ qbuf,
                 const float* __restrict__ rp_W, const float* __restrict__ rp_b,
                 const float* __restrict__ out_W, const float* __restrict__ out_b,
                 float* __restrict__ out)
{
    const int b    = blockIdx.x;
    const int lane = threadIdx.x;
    const float* knb = kn_all  + (size_t)b * 1023 * 64;
    const float* vb  = v_all   + (size_t)b * 1023 * 64;
    const float* v2b = vn2_all + (size_t)b * 1023;

    float M[64];
#pragma unroll
    for (int j = 0; j < 64; ++j) M[j] = 0.f;

    // software pipeline, depth 2
    float4 bufA[16], bufB[16];
    float viA, vnA, viB, vnB;
    load_step(knb, vb, v2b, 0, lane, bufA, viA, vnA);

    for (int t = 0; t < 1022; t += 2) {
        load_step(knb, vb, v2b, t + 1, lane, bufB, viB, vnB);
        scan_step(M, bufA, viA, vnA);
        load_step(knb, vb, v2b, t + 2, lane, bufA, viA, vnA);
        scan_step(M, bufB, viB, vnB);
    }
    scan_step(M, bufA, viA, vnA);   // t = 1022

    // ---- output head: vq = M q ; r = vq @ rp_W + rp_b ; out = r @ out_W + out_b
    float4 qv[16];
    {
        const float4* q4 = (const float4*)(qbuf + b * 64);
#pragma unroll
        for (int w = 0; w < 16; ++w) qv[w] = q4[w];
    }
    float a0 = 0.f, a1 = 0.f, a2 = 0.f, a3 = 0.f;
#pragma unroll
    for (int w = 0; w < 16; ++w) {
        a0 = fmaf(M[4*w+0], qv[w].x, a0);
        a1 = fmaf(M[4*w+1], qv[w].y, a1);
        a2 = fmaf(M[4*w+2], qv[w].z, a2);
        a3 = fmaf(M[4*w+3], qv[w].w, a3);
    }
    float vq = (a0 + a1) + (a2 + a3);

    __shared__ float sh[64];
    sh[lane] = vq;
    __syncthreads();
    float r = rp_b[lane];
#pragma unroll
    for (int ii = 0; ii < 64; ++ii) r = fmaf(sh[ii], rp_W[ii * 64 + lane], r);
    __syncthreads();
    sh[lane] = r;
    __syncthreads();
    float o = out_b[lane];
#pragma unroll
    for (int ii = 0; ii < 64; ++ii) o = fmaf(sh[ii], out_W[ii * 64 + lane], o);
    out[b * 64 + lane] = o;
}

// ---------------------------------------------------------------------------
// Launch. Workspace layout (fp32): kn_all[64*1023*64] | v_all[64*1023*64] |
// vn2_all[64*1023] | qbuf[64*64]  -> ~33.8 MB total.
// ---------------------------------------------------------------------------
extern "C" void kernel_launch(void* const* d_in, const int* in_sizes, int n_in,
                              void* d_out, int out_size, void* d_ws, size_t ws_size,
                              hipStream_t stream)
{
    const int*   seq   = (const int*)  d_in[0];
    const float* embed = (const float*)d_in[1];
    const float* ffW1  = (const float*)d_in[2];
    const float* ffb1  = (const float*)d_in[3];
    const float* ffW2  = (const float*)d_in[4];
    const float* ffb2  = (const float*)d_in[5];
    const float* lng   = (const float*)d_in[6];
    const float* lnb   = (const float*)d_in[7];
    const float* kpW   = (const float*)d_in[8];
    const float* vpW   = (const float*)d_in[9];
    const float* qpW   = (const float*)d_in[10];
    const float* rpW   = (const float*)d_in[11];
    const float* rpb   = (const float*)d_in[12];
    const float* outW  = (const float*)d_in[13];
    const float* outb  = (const float*)d_in[14];
    float* out = (float*)d_out;

    float* kn_all  = (float*)d_ws;
    float* v_all   = kn_all + (size_t)64 * 1023 * 64;
    float* vn2_all = v_all  + (size_t)64 * 1023 * 64;
    float* qbuf    = vn2_all + (size_t)64 * 1023;

    token_kernel<<<2048, 256, 0, stream>>>(seq, embed, ffW1, ffb1, ffW2, ffb2,
                                           lng, lnb, kpW, vpW, qpW,
                                           kn_all, v_all, vn2_all, qbuf);
    scan_kernel<<<64, 64, 0, stream>>>(kn_all, v_all, vn2_all, qbuf,
                                       rpW, rpb, outW, outb, out);
}

// Round 2
// 486.898 us; speedup vs baseline: 3.9499x; 3.9499x over previous
//
#include <hip/hip_runtime.h>
#include <hip/hip_bf16.h>
#include <math.h>

// Problem constants (reference: B=64, L=1024, H=64, VOCAB=64)
#define BB 64
#define LL 1024
#define HH 64

typedef float v4f __attribute__((ext_vector_type(4)));

// ---------------------------------------------------------------------------
// Kernel 1: per-token phase.
// block = 256 threads (4 waves), 32 tokens/block, grid = 65536/32 = 2048.
// Computes hn = LN(h + FF(h)), then writes packed stream knv[b][t] =
// [kn(64) | v(64)] (t<1023) plus vthr[b][t] = 0.4*||v||, or q (t==1023).
// ---------------------------------------------------------------------------
__global__ __launch_bounds__(256, 1)
void token_kernel(const int* __restrict__ seq,
                  const float* __restrict__ embed_W,
                  const float* __restrict__ ff_W1, const float* __restrict__ ff_b1,
                  const float* __restrict__ ff_W2, const float* __restrict__ ff_b2,
                  const float* __restrict__ ln_g, const float* __restrict__ ln_b,
                  const float* __restrict__ kp_W, const float* __restrict__ vp_W,
                  const float* __restrict__ qp_W,
                  float* __restrict__ knv, float* __restrict__ vthr,
                  float* __restrict__ qbuf)
{
    __shared__ __align__(16) float h_s[32][64];    // 8 KB
    __shared__ __align__(16) float t1_s[32][128];  // 16 KB
    __shared__ __align__(16) float hn_s[32][64];   // 8 KB

    const int tid  = threadIdx.x;
    const int tok0 = blockIdx.x * 32;

    // ---- Stage A: embedding gather into LDS ----
#pragma unroll
    for (int k = 0; k < 8; ++k) {
        int e   = k * 256 + tid;
        int tok = e >> 6, i = e & 63;
        int s   = seq[tok0 + tok];
        h_s[tok][i] = embed_W[s * 64 + i];
    }
    __syncthreads();

    // ---- Stage B: FF1 (64 -> 128, ReLU) ----
    {
        const int j = tid & 127;
        const int g = tid >> 7;
        float w1c[64];
#pragma unroll
        for (int ii = 0; ii < 64; ++ii) w1c[ii] = ff_W1[ii * 128 + j];
        const float b1j = ff_b1[j];
#pragma unroll
        for (int tk = 0; tk < 16; ++tk) {
            const int tok = g * 16 + tk;
            const float4* h4 = (const float4*)h_s[tok];
            float a0 = b1j, a1 = 0.f, a2 = 0.f, a3 = 0.f;
#pragma unroll
            for (int w = 0; w < 16; ++w) {
                float4 hv = h4[w];
                a0 = fmaf(hv.x, w1c[4*w+0], a0);
                a1 = fmaf(hv.y, w1c[4*w+1], a1);
                a2 = fmaf(hv.z, w1c[4*w+2], a2);
                a3 = fmaf(hv.w, w1c[4*w+3], a3);
            }
            t1_s[tok][j] = fmaxf((a0 + a1) + (a2 + a3), 0.f);
        }
    }
    __syncthreads();

    // ---- Stage C: FF2 (128 -> 64) + residual + LayerNorm (w2 in 2 halves) ----
    {
        const int i  = tid & 63;
        const int w4 = tid >> 6;
        const float b2i = ff_b2[i];
        const float gi  = ln_g[i];
        const float bi  = ln_b[i];
        float accf[8];
#pragma unroll
        for (int tk = 0; tk < 8; ++tk) accf[tk] = b2i;
#pragma unroll
        for (int h = 0; h < 2; ++h) {
            float w2c[64];
#pragma unroll
            for (int jj = 0; jj < 64; ++jj) w2c[jj] = ff_W2[(h*64 + jj) * 64 + i];
#pragma unroll
            for (int tk = 0; tk < 8; ++tk) {
                const int tok = w4 * 8 + tk;
                const float4* t4 = (const float4*)&t1_s[tok][h*64];
                float a0 = 0.f, a1 = 0.f, a2 = 0.f, a3 = 0.f;
#pragma unroll
                for (int w = 0; w < 16; ++w) {
                    float4 tv = t4[w];
                    a0 = fmaf(tv.x, w2c[4*w+0], a0);
                    a1 = fmaf(tv.y, w2c[4*w+1], a1);
                    a2 = fmaf(tv.z, w2c[4*w+2], a2);
                    a3 = fmaf(tv.w, w2c[4*w+3], a3);
                }
                accf[tk] += (a0 + a1) + (a2 + a3);
            }
        }
#pragma unroll
        for (int tk = 0; tk < 8; ++tk) {
            const int tok = w4 * 8 + tk;
            float x = h_s[tok][i] + accf[tk];
            float s = x;
#pragma unroll
            for (int m = 32; m > 0; m >>= 1) s += __shfl_xor(s, m);
            float mu = s * (1.f / 64.f);
            float d  = x - mu;
            float s2 = d * d;
#pragma unroll
            for (int m = 32; m > 0; m >>= 1) s2 += __shfl_xor(s2, m);
            float var = s2 * (1.f / 64.f);
            hn_s[tok][i] = d / sqrtf(var + 1e-5f) * gi + bi;
        }
    }
    __syncthreads();

    // ---- Stage D: kn/v into packed stream (t<1023) OR q (t==1023) ----
    {
        const int i  = tid & 63;
        const int w4 = tid >> 6;
        float kc[64], vc[64];
#pragma unroll
        for (int ii = 0; ii < 64; ++ii) {
            kc[ii] = kp_W[ii * 64 + i];
            vc[ii] = vp_W[ii * 64 + i];
        }
#pragma unroll
        for (int tk = 0; tk < 8; ++tk) {
            const int tok = w4 * 8 + tk;
            const int tg  = tok0 + tok;
            const int b   = tg >> 10;
            const int t   = tg & 1023;
            const float4* hn4 = (const float4*)hn_s[tok];
            if (t < 1023) {
                float ka0=0.f,ka1=0.f,ka2=0.f,ka3=0.f;
                float va0=0.f,va1=0.f,va2=0.f,va3=0.f;
#pragma unroll
                for (int w = 0; w < 16; ++w) {
                    float4 hv = hn4[w];
                    ka0 = fmaf(hv.x, kc[4*w+0], ka0);
                    ka1 = fmaf(hv.y, kc[4*w+1], ka1);
                    ka2 = fmaf(hv.z, kc[4*w+2], ka2);
                    ka3 = fmaf(hv.w, kc[4*w+3], ka3);
                    va0 = fmaf(hv.x, vc[4*w+0], va0);
                    va1 = fmaf(hv.y, vc[4*w+1], va1);
                    va2 = fmaf(hv.z, vc[4*w+2], va2);
                    va3 = fmaf(hv.w, vc[4*w+3], va3);
                }
                float ka = (ka0 + ka1) + (ka2 + ka3);
                float va = (va0 + va1) + (va2 + va3);
                float kn2 = ka * ka, vn2 = va * va;
#pragma unroll
                for (int m = 32; m > 0; m >>= 1) {
                    kn2 += __shfl_xor(kn2, m);
                    vn2 += __shfl_xor(vn2, m);
                }
                float knorm = fmaxf(sqrtf(kn2), 1e-12f);
                size_t row = ((size_t)b * 1024 + t) * 128;
                knv[row + i]      = ka / knorm;
                knv[row + 64 + i] = va;
                if (i == 0) vthr[b * 1024 + t] = 0.4f * sqrtf(vn2);
            } else {
                float qa0=0.f,qa1=0.f,qa2=0.f,qa3=0.f;
#pragma unroll
                for (int w = 0; w < 16; ++w) {
                    float4 hv = hn4[w];
                    qa0 = fmaf(hv.x, qp_W[(4*w+0)*64 + i], qa0);
                    qa1 = fmaf(hv.y, qp_W[(4*w+1)*64 + i], qa1);
                    qa2 = fmaf(hv.z, qp_W[(4*w+2)*64 + i], qa2);
                    qa3 = fmaf(hv.w, qp_W[(4*w+3)*64 + i], qa3);
                }
                qbuf[b * 64 + i] = (qa0 + qa1) + (qa2 + qa3);
            }
        }
    }
}

// ---------------------------------------------------------------------------
// Kernel 2: sequential fast-weight scan + output head.
// grid = 64 (one block/batch), block = 64 (one wave). Lane i owns M row i
// as 16 named v4f registers. kn/v stream staged through LDS via
// global_load_lds (width 16), double-buffered 16-step chunks.
// ---------------------------------------------------------------------------

template<int CTRL>
__device__ __forceinline__ float dppadd(float x) {
    int y = __builtin_amdgcn_update_dpp(0, __float_as_int(x), CTRL, 0xF, 0xF, true);
    return x + __int_as_float(y);
}

#define RPT16(F) F(0) F(1) F(2) F(3) F(4) F(5) F(6) F(7) \
                 F(8) F(9) F(10) F(11) F(12) F(13) F(14) F(15)

#define INITM(i) v4f m##i = {0.f, 0.f, 0.f, 0.f};
#define LOADK(i) v4f k##i = kk[i];
#define DOTG(A, I0, I1, I2, I3) \
    v4f acc##A = __builtin_elementwise_fma(m##I0, k##I0, \
                 __builtin_elementwise_fma(m##I1, k##I1, \
                 __builtin_elementwise_fma(m##I2, k##I2, m##I3 * k##I3)));
#define UPD(i) m##i = __builtin_elementwise_fma(gdv, k##i, m##i);
#define QFMA(i) accq = __builtin_elementwise_fma(m##i, qq[i], accq);

// One scan step: reads kn row (LDS broadcast b128), v element, thr; updates M.
// Uses `lane` from enclosing scope.
#define STEP(BASE, S, THRP) do { \
    const v4f* kk = (const v4f*)((BASE) + (S) * 128); \
    RPT16(LOADK) \
    float vv = ((const float*)(BASE))[(S) * 128 + 64 + lane]; \
    float th = (THRP)[S]; \
    DOTG(0, 0, 4, 8, 12) DOTG(1, 1, 5, 9, 13) \
    DOTG(2, 2, 6, 10, 14) DOTG(3, 3, 7, 11, 15) \
    v4f ts_ = (acc0 + acc1) + (acc2 + acc3); \
    float vp_ = (ts_.x + ts_.y) + (ts_.z + ts_.w); \
    float d_ = vv - vp_; \
    float x_ = d_ * d_; \
    x_ = dppadd<0x111>(x_); x_ = dppadd<0x112>(x_); \
    x_ = dppadd<0x114>(x_); x_ = dppadd<0x118>(x_); \
    x_ = dppadd<0x142>(x_); x_ = dppadd<0x143>(x_); \
    float e_ = __int_as_float(__builtin_amdgcn_readlane(__float_as_int(x_), 63)); \
    float gd_ = (sqrtf(e_) > th) ? d_ : 0.0f; \
    v4f gdv = {gd_, gd_, gd_, gd_}; \
    RPT16(UPD) \
} while (0)

#define CHUNK16(B, T) \
    STEP(B, 0, T);  STEP(B, 1, T);  STEP(B, 2, T);  STEP(B, 3, T); \
    STEP(B, 4, T);  STEP(B, 5, T);  STEP(B, 6, T);  STEP(B, 7, T); \
    STEP(B, 8, T);  STEP(B, 9, T);  STEP(B, 10, T); STEP(B, 11, T); \
    STEP(B, 12, T); STEP(B, 13, T); STEP(B, 14, T); STEP(B, 15, T);

#define CHUNK15(B, T) \
    STEP(B, 0, T);  STEP(B, 1, T);  STEP(B, 2, T);  STEP(B, 3, T); \
    STEP(B, 4, T);  STEP(B, 5, T);  STEP(B, 6, T);  STEP(B, 7, T); \
    STEP(B, 8, T);  STEP(B, 9, T);  STEP(B, 10, T); STEP(B, 11, T); \
    STEP(B, 12, T); STEP(B, 13, T); STEP(B, 14, T);

// async copy: 1024 B contiguous global -> contiguous LDS (one inst)
__device__ __forceinline__ void gl2lds_1k(const float* g, float* l, int lane) {
    __builtin_amdgcn_global_load_lds(
        (const __attribute__((address_space(1))) void*)(g + lane * 4),
        (__attribute__((address_space(3))) void*)l, 16, 0, 0);
}

__device__ __forceinline__ void prefetch_chunk(const float* g, float* l, int lane) {
#pragma unroll
    for (int w = 0; w < 8; ++w)
        gl2lds_1k(g + w * 256, l + w * 256, lane);
}

__global__ __launch_bounds__(64, 1)
void scan_kernel(const float* __restrict__ knv,
                 const float* __restrict__ vthr,
                 const float* __restrict__ qbuf,
                 const float* __restrict__ rp_W, const float* __restrict__ rp_b,
                 const float* __restrict__ out_W, const float* __restrict__ out_b,
                 float* __restrict__ out)
{
    const int b    = blockIdx.x;
    const int lane = threadIdx.x;
    const float* knvb = knv  + (size_t)b * 1024 * 128;
    const float* thrb = vthr + (size_t)b * 1024;

    __shared__ __align__(16) float thr_s[1024];     // 4 KB
    __shared__ __align__(16) float buf[2][2048];    // 2 x 8 KB (16 steps each)
    __shared__ float sh[64];

    RPT16(INITM)

    // prefetch: thr (4 insts), chunk 0 (8), chunk 1 (8) -> 20 outstanding
#pragma unroll
    for (int w = 0; w < 4; ++w) gl2lds_1k(thrb + w * 256, thr_s + w * 256, lane);
    prefetch_chunk(knvb, buf[0], lane);
    prefetch_chunk(knvb + 2048, buf[1], lane);

#pragma unroll 1
    for (int c = 0; c < 63; ++c) {
        // chunk c's 8 loads (and everything older) done; chunk c+1 in flight
        asm volatile("s_waitcnt vmcnt(8)" ::: "memory");
        const float* bb = buf[c & 1];
        const float* tp = &thr_s[c * 16];
        CHUNK16(bb, tp)
        if (c < 62)
            prefetch_chunk(knvb + (size_t)(c + 2) * 2048, buf[c & 1], lane);
    }
    asm volatile("s_waitcnt vmcnt(0)" ::: "memory");
    {   // last chunk: steps t = 1008..1022 (15 steps), buffer 1
        const float* bb = buf[1];
        const float* tp = &thr_s[63 * 16];
        CHUNK15(bb, tp)
    }

    // ---- output head: vq = M q ; r = vq @ rp_W + rp_b ; out = r @ out_W + out_b
    const v4f* qq = (const v4f*)(qbuf + b * 64);
    v4f accq = {0.f, 0.f, 0.f, 0.f};
    RPT16(QFMA)
    float vq = (accq.x + accq.y) + (accq.z + accq.w);

    sh[lane] = vq;
    __syncthreads();
    float r = rp_b[lane];
#pragma unroll
    for (int ii = 0; ii < 64; ++ii) r = fmaf(sh[ii], rp_W[ii * 64 + lane], r);
    __syncthreads();
    sh[lane] = r;
    __syncthreads();
    float o = out_b[lane];
#pragma unroll
    for (int ii = 0; ii < 64; ++ii) o = fmaf(sh[ii], out_W[ii * 64 + lane], o);
    out[b * 64 + lane] = o;
}

// ---------------------------------------------------------------------------
// Launch. Workspace (fp32): knv[64][1024][128] (33.55 MB, t=1023 row unused) |
// vthr[64][1024] (262 KB) | qbuf[64][64]. Total ~33.9 MB.
// ---------------------------------------------------------------------------
extern "C" void kernel_launch(void* const* d_in, const int* in_sizes, int n_in,
                              void* d_out, int out_size, void* d_ws, size_t ws_size,
                              hipStream_t stream)
{
    const int*   seq   = (const int*)  d_in[0];
    const float* embed = (const float*)d_in[1];
    const float* ffW1  = (const float*)d_in[2];
    const float* ffb1  = (const float*)d_in[3];
    const float* ffW2  = (const float*)d_in[4];
    const float* ffb2  = (const float*)d_in[5];
    const float* lng   = (const float*)d_in[6];
    const float* lnb   = (const float*)d_in[7];
    const float* kpW   = (const float*)d_in[8];
    const float* vpW   = (const float*)d_in[9];
    const float* qpW   = (const float*)d_in[10];
    const float* rpW   = (const float*)d_in[11];
    const float* rpb   = (const float*)d_in[12];
    const float* outW  = (const float*)d_in[13];
    const float* outb  = (const float*)d_in[14];
    float* out = (float*)d_out;

    float* knv  = (float*)d_ws;
    float* vthr = knv  + (size_t)64 * 1024 * 128;
    float* qbuf = vthr + (size_t)64 * 1024;

    token_kernel<<<2048, 256, 0, stream>>>(seq, embed, ffW1, ffb1, ffW2, ffb2,
                                           lng, lnb, kpW, vpW, qpW,
                                           knv, vthr, qbuf);
    scan_kernel<<<64, 64, 0, stream>>>(knv, vthr, qbuf,
                                       rpW, rpb, outW, outb, out);
}